// Round 11
// baseline (59.923 us; speedup 1.0000x reference)
//
#include <hip/hip_runtime.h>
#include <math.h>

#define NBOX 2048
#define NBATCH 8
#define MAX_INST 100
#define MIN_CONF 0.15f
#define NMS_THR 0.3f
#define BLOCK 512
#define NWIN 32        // NBOX / 64

typedef unsigned long long ull;

// Decode one box exactly in the reference's f32 op order (no FMA contraction).
__device__ inline float4 decode_box(float4 r, float4 d,
                                    float wy1, float wx1, float wy2, float wx2) {
    float h  = __fsub_rn(r.z, r.x);
    float w  = __fsub_rn(r.w, r.y);
    float dy = __fmul_rn(d.x, 0.1f);
    float dx = __fmul_rn(d.y, 0.1f);
    float dh = __fmul_rn(d.z, 0.2f);
    float dw = __fmul_rn(d.w, 0.2f);
    float cy = __fadd_rn(__fadd_rn(r.x, __fmul_rn(0.5f, h)), __fmul_rn(dy, h));
    float cx = __fadd_rn(__fadd_rn(r.y, __fmul_rn(0.5f, w)), __fmul_rn(dx, w));
    float h2 = __fmul_rn(h, expf(dh));
    float w2 = __fmul_rn(w, expf(dw));
    float y1 = __fsub_rn(cy, __fmul_rn(0.5f, h2));
    float x1 = __fsub_rn(cx, __fmul_rn(0.5f, w2));
    float y2 = __fadd_rn(y1, h2);
    float x2 = __fadd_rn(x1, w2);
    float4 b;
    b.x = fminf(fmaxf(y1, wy1), wy2);
    b.y = fminf(fmaxf(x1, wx1), wx2);
    b.z = fminf(fmaxf(y2, wy1), wy2);
    b.w = fminf(fmaxf(x2, wx1), wx2);
    return b;
}

// IoU with precomputed areas; identical f32 op order to the reference.
__device__ inline float iou_pa(float ax, float ay, float az, float aw2, float areaA,
                               float4 b, float areaB) {
    float iy1 = fmaxf(ax,  b.x);
    float ix1 = fmaxf(ay,  b.y);
    float iy2 = fminf(az,  b.z);
    float ix2 = fminf(aw2, b.w);
    float ih = fmaxf(__fsub_rn(iy2, iy1), 0.0f);
    float iw = fmaxf(__fsub_rn(ix2, ix1), 0.0f);
    float inter = __fmul_rn(ih, iw);
    float uni = __fadd_rn(__fsub_rn(__fadd_rn(areaA, areaB), inter), 1e-8f);
    return __fdiv_rn(inter, uni);
}

// Area with the reference's exact ops (bitwise == stored sarea).
__device__ inline float area_of(float4 a) {
    return __fmul_rn(__fsub_rn(a.z, a.x), __fsub_rn(a.w, a.y));
}

__device__ inline ull shfl_xor64(ull x, int d) {
    unsigned lo = (unsigned)x, hi = (unsigned)(x >> 32);
    lo = __shfl_xor(lo, d);
    hi = __shfl_xor(hi, d);
    return ((ull)hi << 32) | lo;
}

__device__ inline void cmpsel(ull& a, ull& b, bool takeMinA) {
    ull mn = a < b ? a : b;
    ull mx = a < b ? b : a;
    a = takeMinA ? mn : mx;
    b = takeMinA ? mx : mn;
}

__device__ inline float readlane_f(float x, int sl) {
    return __uint_as_float((unsigned)__builtin_amdgcn_readlane((int)__float_as_uint(x), sl));
}

__global__ __launch_bounds__(BLOCK)
void detect_refine_kernel(const float* __restrict__ rois,
                          const float* __restrict__ scores_in,
                          const float* __restrict__ deltas,
                          const float* __restrict__ window,
                          float* __restrict__ out) {
    const int b    = blockIdx.x;
    const int tid  = threadIdx.x;
    const int lane = tid & 63;
    const int wid  = tid >> 6;

    __shared__ ull    keys[NBOX];          // 16 KiB  sort scratch
    __shared__ float4 sbox[NBOX];          // 32 KiB  decoded boxes, SORTED rank
    __shared__ float  sarea[NBOX];         //  8 KiB
    __shared__ float  sscore[NBOX];        //  8 KiB
    __shared__ ull    sdead[2][7];         // [parity][wave 1..7]
    __shared__ float4 skept[MAX_INST];
    __shared__ float  skeptsc[MAX_INST];
    __shared__ int    s_cnt[2];            // parity: count visible to pre-checkers
    __shared__ int    s_stop[2];           // parity: stop flag per iteration
    __shared__ int    s_final;

    const float wy1 = window[b * 4 + 0];
    const float wx1 = window[b * 4 + 1];
    const float wy2 = window[b * 4 + 2];
    const float wx2 = window[b * 4 + 3];

    float* outb = out + (size_t)b * MAX_INST * 5;

    // ---- Phase A: register bitonic sort of (score,idx) keys ----
    const int e0 = tid * 4;
    ull v[4];
    {
        float4 sc = ((const float4*)(scores_in + (size_t)b * NBOX))[tid];
        float s4[4] = {sc.x, sc.y, sc.z, sc.w};
#pragma unroll
        for (int s = 0; s < 4; ++s) {
            unsigned u = __float_as_uint(s4[s]);
            u = (u & 0x80000000u) ? ~u : (u | 0x80000000u);
            v[s] = ((ull)(~u) << 32) | (unsigned)(e0 + s);
        }
    }
    for (unsigned k = 2; k <= NBOX; k <<= 1) {
        if (k >= 512) {
#pragma unroll
            for (int s = 0; s < 4; ++s) keys[e0 + s] = v[s];
            __syncthreads();
            for (unsigned j = k >> 1; j >= 256; j >>= 1) {
                for (int t = tid; t < NBOX / 2; t += BLOCK) {
                    int i = 2 * t - (t & (j - 1));
                    int p = i | j;
                    bool up = ((i & k) == 0);
                    ull a = keys[i], c = keys[p];
                    bool sw = up ? (a > c) : (a < c);
                    if (sw) { keys[i] = c; keys[p] = a; }
                }
                __syncthreads();
            }
#pragma unroll
            for (int s = 0; s < 4; ++s) v[s] = keys[e0 + s];
        }
        unsigned jstart = ((k >> 1) > 128u) ? 128u : (k >> 1);
        for (unsigned j = jstart; j >= 4; j >>= 1) {
            int d = (int)(j >> 2);
#pragma unroll
            for (int s = 0; s < 4; ++s) {
                ull p = shfl_xor64(v[s], d);
                int e = e0 + s;
                bool takeMin = (((e & j) == 0) == ((e & k) == 0));
                v[s] = takeMin ? (v[s] < p ? v[s] : p) : (v[s] > p ? v[s] : p);
            }
        }
        if (k >= 4) {   // j == 2
            bool up = ((e0 & k) == 0);
            cmpsel(v[0], v[2], up);
            cmpsel(v[1], v[3], up);
        }
        {               // j == 1
            bool upA = ((e0 & k) == 0);
            bool upB = (((e0 + 2) & k) == 0);
            cmpsel(v[0], v[1], upA);
            cmpsel(v[2], v[3], upB);
        }
    }

    // ---- Phase P: permute+decode into SORTED-rank arrays ----
#pragma unroll
    for (int s = 0; s < 4; ++s) {
        int r = e0 + s;
        int oi = (int)(v[s] & 0xFFFFFFFFull);
        float4 rr = ((const float4*)rois)[b * NBOX + oi];
        float4 dd = ((const float4*)deltas)[b * NBOX + oi];
        float4 bb = decode_box(rr, dd, wy1, wx1, wy2, wx2);
        sbox[r]   = bb;
        sarea[r]  = area_of(bb);
        sscore[r] = scores_in[b * NBOX + oi];
    }
    if (tid == 0) { s_cnt[0] = 0; s_stop[0] = 0; s_stop[1] = 0; s_final = 0; }
    __syncthreads();

    // ---- Phase C: one barrier per window; chain(w) on wave 0 overlapped
    //      with pre-dead-check(w+1) on waves 1-7. ----
    int count = 0;                 // exact only on wave 0
    float4 pk;  float pka = 0.f;   // wave 0: last window's keeps, lane-distributed
    int m_prev = 0;

    for (int w = 0; w < NWIN; ++w) {
        const int par = w & 1, pnx = par ^ 1;

        if (wid == 0) {
            // Load this window's candidates (issue early).
            float4 cb = sbox[(w << 6) + lane];
            float  ca = sarea[(w << 6) + lane];
            float  cs = sscore[(w << 6) + lane];

            // Pre-mask: window 0 from own scores; else from waves 1-7 (last iter).
            ull dead;
            if (w == 0) {
                dead = __ballot(cs < MIN_CONF);
            } else {
                dead = sdead[par][0];
#pragma unroll
                for (int q = 1; q < 7; ++q) dead |= sdead[par][q];
            }
            // Fixup vs keeps found in the PREVIOUS window (registers only).
            for (int j = 0; j < m_prev; ++j) {
                float kx = readlane_f(pk.x, j);
                float ky = readlane_f(pk.y, j);
                float kz = readlane_f(pk.z, j);
                float kw = readlane_f(pk.w, j);
                float ka = readlane_f(pka,  j);
                dead |= __ballot(iou_pa(kx, ky, kz, kw, ka, cb, ca) > NMS_THR);
            }

            // Greedy chain.
            ull alive = ~dead;
            int m = 0;
            const int maxm = MAX_INST - count;
            while (alive && m < maxm) {
                int il = __builtin_amdgcn_readfirstlane((int)__builtin_ctzll(alive));
                float kx = readlane_f(cb.x, il);
                float ky = readlane_f(cb.y, il);
                float kz = readlane_f(cb.z, il);
                float kw = readlane_f(cb.w, il);
                float ka = readlane_f(ca,   il);
                float ks = readlane_f(cs,   il);
                if (lane == 0) {
                    skept[count + m]   = make_float4(kx, ky, kz, kw);
                    skeptsc[count + m] = ks;
                }
                if (lane == m) { pk = make_float4(kx, ky, kz, kw); pka = ka; }
                ++m;
                ull sup = __ballot(iou_pa(kx, ky, kz, kw, ka, cb, ca) > NMS_THR);
                alive &= ~sup;
                alive &= ~(1ull << il);
            }
            m_prev = m;
            count += m;
            if (lane == 0) {
                s_cnt[pnx]  = count;                       // for pre-checkers @ w+1
                s_stop[par] = (count >= MAX_INST) || (w + 1 >= NWIN);
                s_final     = count;
            }
        } else if (w + 1 < NWIN) {
            // Pre-dead-check window w+1 vs skept[0..cnt), 7 waves, 4-way unroll.
            const int nw = ((w + 1) << 6) + lane;
            float4 cb = sbox[nw];
            float  ca = sarea[nw];
            float  cs = sscore[nw];
            const int cnt = s_cnt[par];    // count BEFORE wave 0's current chain
            bool dp = (cs < MIN_CONF);
            int k = wid - 1;               // 0..6, stride 7
            for (; k + 21 < cnt; k += 28) {
                float4 a0 = skept[k];
                float4 a1 = skept[k + 7];
                float4 a2 = skept[k + 14];
                float4 a3 = skept[k + 21];
                dp |= (iou_pa(a0.x, a0.y, a0.z, a0.w, area_of(a0), cb, ca) > NMS_THR);
                dp |= (iou_pa(a1.x, a1.y, a1.z, a1.w, area_of(a1), cb, ca) > NMS_THR);
                dp |= (iou_pa(a2.x, a2.y, a2.z, a2.w, area_of(a2), cb, ca) > NMS_THR);
                dp |= (iou_pa(a3.x, a3.y, a3.z, a3.w, area_of(a3), cb, ca) > NMS_THR);
            }
            for (; k < cnt; k += 7) {
                float4 a0 = skept[k];
                dp |= (iou_pa(a0.x, a0.y, a0.z, a0.w, area_of(a0), cb, ca) > NMS_THR);
            }
            ull bal = __ballot(dp);
            if (lane == 0) sdead[pnx][wid - 1] = bal;
        }
        __syncthreads();
        if (s_stop[par]) break;
    }

    // ---- Epilogue: write all MAX_INST rows (kept values, zeros elsewhere) ----
    const int fin = s_final;
    for (int i = tid; i < MAX_INST * 5; i += BLOCK) {
        int r = i / 5, c = i % 5;
        float vv = 0.0f;
        if (r < fin) {
            float4 kb = skept[r];
            vv = (c == 0) ? kb.x
               : (c == 1) ? kb.y
               : (c == 2) ? kb.z
               : (c == 3) ? kb.w
               :            skeptsc[r];
        }
        outb[i] = vv;
    }
}

extern "C" void kernel_launch(void* const* d_in, const int* in_sizes, int n_in,
                              void* d_out, int out_size, void* d_ws, size_t ws_size,
                              hipStream_t stream) {
    const float* rois    = (const float*)d_in[0];
    const float* scores  = (const float*)d_in[1];
    const float* deltas  = (const float*)d_in[2];
    const float* window  = (const float*)d_in[3];
    float* out = (float*)d_out;
    detect_refine_kernel<<<NBATCH, BLOCK, 0, stream>>>(rois, scores, deltas, window, out);
}

// Round 12
// 48.009 us; speedup vs baseline: 1.2482x; 1.2482x over previous
//
#include <hip/hip_runtime.h>
#include <math.h>

#define NBOX 2048
#define NBATCH 8
#define MAX_INST 100
#define MIN_CONF 0.15f
#define NMS_THR 0.3f
#define BLOCK 512
#define NWAVE 8

typedef unsigned long long ull;

// Decode one box exactly in the reference's f32 op order (no FMA contraction).
__device__ inline float4 decode_box(float4 r, float4 d,
                                    float wy1, float wx1, float wy2, float wx2) {
    float h  = __fsub_rn(r.z, r.x);
    float w  = __fsub_rn(r.w, r.y);
    float dy = __fmul_rn(d.x, 0.1f);
    float dx = __fmul_rn(d.y, 0.1f);
    float dh = __fmul_rn(d.z, 0.2f);
    float dw = __fmul_rn(d.w, 0.2f);
    float cy = __fadd_rn(__fadd_rn(r.x, __fmul_rn(0.5f, h)), __fmul_rn(dy, h));
    float cx = __fadd_rn(__fadd_rn(r.y, __fmul_rn(0.5f, w)), __fmul_rn(dx, w));
    float h2 = __fmul_rn(h, expf(dh));
    float w2 = __fmul_rn(w, expf(dw));
    float y1 = __fsub_rn(cy, __fmul_rn(0.5f, h2));
    float x1 = __fsub_rn(cx, __fmul_rn(0.5f, w2));
    float y2 = __fadd_rn(y1, h2);
    float x2 = __fadd_rn(x1, w2);
    float4 b;
    b.x = fminf(fmaxf(y1, wy1), wy2);
    b.y = fminf(fmaxf(x1, wx1), wx2);
    b.z = fminf(fmaxf(y2, wy1), wy2);
    b.w = fminf(fmaxf(x2, wx1), wx2);
    return b;
}

// IoU with precomputed areas; identical f32 op order to the reference.
__device__ inline float iou_pa(float ax, float ay, float az, float aw2, float areaA,
                               float4 b, float areaB) {
    float iy1 = fmaxf(ax,  b.x);
    float ix1 = fmaxf(ay,  b.y);
    float iy2 = fminf(az,  b.z);
    float ix2 = fminf(aw2, b.w);
    float ih = fmaxf(__fsub_rn(iy2, iy1), 0.0f);
    float iw = fmaxf(__fsub_rn(ix2, ix1), 0.0f);
    float inter = __fmul_rn(ih, iw);
    float uni = __fadd_rn(__fsub_rn(__fadd_rn(areaA, areaB), inter), 1e-8f);
    return __fdiv_rn(inter, uni);
}

// Area with the reference's exact ops.
__device__ inline float area_of(float4 a) {
    return __fmul_rn(__fsub_rn(a.z, a.x), __fsub_rn(a.w, a.y));
}

__device__ inline ull shfl_xor64(ull x, int d) {
    unsigned lo = (unsigned)x, hi = (unsigned)(x >> 32);
    lo = __shfl_xor(lo, d);
    hi = __shfl_xor(hi, d);
    return ((ull)hi << 32) | lo;
}

__device__ inline void cmpsel(ull& a, ull& b, bool takeMinA) {
    ull mn = a < b ? a : b;
    ull mx = a < b ? b : a;
    a = takeMinA ? mn : mx;
    b = takeMinA ? mx : mn;
}

__device__ inline float readlane_f(float x, int sl) {
    return __uint_as_float((unsigned)__builtin_amdgcn_readlane((int)__float_as_uint(x), sl));
}

__global__ __launch_bounds__(BLOCK)
void detect_refine_kernel(const float* __restrict__ rois,
                          const float* __restrict__ scores_in,
                          const float* __restrict__ deltas,
                          const float* __restrict__ window,
                          float* __restrict__ out) {
    const int b    = blockIdx.x;
    const int tid  = threadIdx.x;
    const int lane = tid & 63;
    const int wid  = tid >> 6;

    __shared__ ull    keys[NBOX];           // 16 KiB  (~score_bits)<<32 | orig_idx
    __shared__ float4 sboxes[NBOX];         // 32 KiB  decoded boxes, ORIGINAL idx
    __shared__ float  sscores[NBOX];        //  8 KiB  ORIGINAL idx
    __shared__ ull    dead8[NWAVE];
    __shared__ float4 skept[MAX_INST];      //  1.6 KiB
    __shared__ float  skeptsc[MAX_INST];
    __shared__ float  skeptar[MAX_INST];
    __shared__ int    s_m;

    const float wy1 = window[b * 4 + 0];
    const float wx1 = window[b * 4 + 1];
    const float wy2 = window[b * 4 + 2];
    const float wx2 = window[b * 4 + 3];

    float* outb = out + (size_t)b * MAX_INST * 5;

    // ---- Phase A1: coalesced load + decode, stored by ORIGINAL index ----
    for (int e = tid; e < NBOX; e += BLOCK) {
        float4 r = ((const float4*)rois)[b * NBOX + e];
        float4 d = ((const float4*)deltas)[b * NBOX + e];
        float  s = scores_in[b * NBOX + e];
        sboxes[e]  = decode_box(r, d, wy1, wx1, wy2, wx2);
        sscores[e] = s;
    }

    // ---- Phase A2: sort keys in registers (4 consecutive elements/thread) ----
    const int e0 = tid * 4;
    ull v[4];
    {
        float4 sc = ((const float4*)(scores_in + (size_t)b * NBOX))[tid];
        float s4[4] = {sc.x, sc.y, sc.z, sc.w};
#pragma unroll
        for (int s = 0; s < 4; ++s) {
            unsigned u = __float_as_uint(s4[s]);
            u = (u & 0x80000000u) ? ~u : (u | 0x80000000u);
            v[s] = ((ull)(~u) << 32) | (unsigned)(e0 + s);
        }
    }

    // ---- Phase B: bitonic sort ascending (= score descending, stable) ----
    for (unsigned k = 2; k <= NBOX; k <<= 1) {
        if (k >= 512) {
#pragma unroll
            for (int s = 0; s < 4; ++s) keys[e0 + s] = v[s];
            __syncthreads();
            for (unsigned j = k >> 1; j >= 256; j >>= 1) {
                for (int t = tid; t < NBOX / 2; t += BLOCK) {
                    int i = 2 * t - (t & (j - 1));
                    int p = i | j;
                    bool up = ((i & k) == 0);
                    ull a = keys[i], c = keys[p];
                    bool sw = up ? (a > c) : (a < c);
                    if (sw) { keys[i] = c; keys[p] = a; }
                }
                __syncthreads();
            }
#pragma unroll
            for (int s = 0; s < 4; ++s) v[s] = keys[e0 + s];
        }
        unsigned jstart = ((k >> 1) > 128u) ? 128u : (k >> 1);
        for (unsigned j = jstart; j >= 4; j >>= 1) {
            int d = (int)(j >> 2);
#pragma unroll
            for (int s = 0; s < 4; ++s) {
                ull p = shfl_xor64(v[s], d);
                int e = e0 + s;
                bool takeMin = (((e & j) == 0) == ((e & k) == 0));
                v[s] = takeMin ? (v[s] < p ? v[s] : p) : (v[s] > p ? v[s] : p);
            }
        }
        if (k >= 4) {   // j == 2
            bool up = ((e0 & k) == 0);
            cmpsel(v[0], v[2], up);
            cmpsel(v[1], v[3], up);
        }
        {               // j == 1
            bool upA = ((e0 & k) == 0);
            bool upB = (((e0 + 2) & k) == 0);
            cmpsel(v[0], v[1], upA);
            cmpsel(v[2], v[3], upB);
        }
    }
#pragma unroll
    for (int s = 0; s < 4; ++s) keys[e0 + s] = v[s];
    __syncthreads();

    // ---- Phase C: window-batched greedy NMS, maskless register chain ----
    int count = 0;
    for (int base = 0; base < NBOX && count < MAX_INST; base += 64) {
        // Candidate for this lane (same in every wave).
        int    oi = (int)(keys[base + lane] & 0xFFFFFFFFull);
        float4 bj = sboxes[oi];
        float  sj = sscores[oi];
        float  aj = area_of(bj);

        // Dead-check vs kept list, strided across waves, 2-way unrolled.
        bool deadp = (sj < MIN_CONF);
        {
            int k = wid;
            for (; k + 8 < count; k += 16) {
                float4 k1 = skept[k];     float a1 = skeptar[k];
                float4 k2 = skept[k + 8]; float a2 = skeptar[k + 8];
                deadp |= (iou_pa(k1.x, k1.y, k1.z, k1.w, a1, bj, aj) > NMS_THR);
                deadp |= (iou_pa(k2.x, k2.y, k2.z, k2.w, a2, bj, aj) > NMS_THR);
            }
            if (k < count) {
                float4 k1 = skept[k]; float a1 = skeptar[k];
                deadp |= (iou_pa(k1.x, k1.y, k1.z, k1.w, a1, bj, aj) > NMS_THR);
            }
        }
        ull bal = __ballot(deadp);
        if (lane == 0) dead8[wid] = bal;
        __syncthreads();

        // Wave 0: maskless greedy chain — readlane broadcasts, 1 IoU per lane.
        if (wid == 0) {
            ull dead = dead8[0];
#pragma unroll
            for (int w2 = 1; w2 < NWAVE; ++w2) dead |= dead8[w2];
            ull alive = ~dead;
            int m = 0;
            const int maxm = MAX_INST - count;
            while (alive && m < maxm) {
                int il = __builtin_amdgcn_readfirstlane((int)__builtin_ctzll(alive));
                float kx = readlane_f(bj.x, il);
                float ky = readlane_f(bj.y, il);
                float kz = readlane_f(bj.z, il);
                float kw = readlane_f(bj.w, il);
                float ka = readlane_f(aj,   il);
                float ks = readlane_f(sj,   il);
                if (lane == 0) {
                    skept[count + m]   = make_float4(kx, ky, kz, kw);
                    skeptsc[count + m] = ks;
                    skeptar[count + m] = ka;
                }
                ++m;
                ull sup = __ballot(iou_pa(kx, ky, kz, kw, ka, bj, aj) > NMS_THR);
                alive &= ~sup;
                alive &= ~(1ull << il);
            }
            if (lane == 0) s_m = m;
        }
        __syncthreads();
        count += s_m;
    }

    // ---- Epilogue: write all MAX_INST rows (kept values, zeros elsewhere) ----
    for (int i = tid; i < MAX_INST * 5; i += BLOCK) {
        int r = i / 5, c = i % 5;
        float vout = 0.0f;
        if (r < count) {
            float4 bb = skept[r];
            vout = (c == 0) ? bb.x
                 : (c == 1) ? bb.y
                 : (c == 2) ? bb.z
                 : (c == 3) ? bb.w
                 :            skeptsc[r];
        }
        outb[i] = vout;
    }
}

extern "C" void kernel_launch(void* const* d_in, const int* in_sizes, int n_in,
                              void* d_out, int out_size, void* d_ws, size_t ws_size,
                              hipStream_t stream) {
    const float* rois    = (const float*)d_in[0];
    const float* scores  = (const float*)d_in[1];
    const float* deltas  = (const float*)d_in[2];
    const float* window  = (const float*)d_in[3];
    float* out = (float*)d_out;
    detect_refine_kernel<<<NBATCH, BLOCK, 0, stream>>>(rois, scores, deltas, window, out);
}